// Round 1
// 86.777 us; speedup vs baseline: 1.0327x; 1.0327x over previous
//
#include <hip/hip_runtime.h>
#include <stdint.h>

#define N_EXPERTS 20
#define DIM 32
#define SPB 256            // samples per block
#define MAIN_T 512         // 8 waves per block
#define MROW 40            // LDS M row stride in shorts (80 B: 16B-aligned rows, 2-way max on b128)
#define XROW 40            // LDS x row stride in shorts (80 B, same property)
#define MAX_TILES 48

using frag_ab = __attribute__((ext_vector_type(8))) short;  // 8 bf16
using frag_cd = __attribute__((ext_vector_type(4))) float;  // 4 fp32

static __device__ __forceinline__ short f2bf(float f) {
    union { float f; uint32_t u; } v; v.f = f;
    uint32_t u = v.u;
    return (short)(uint16_t)((u + 0x7FFFu + ((u >> 16) & 1u)) >> 16);  // RNE
}

// ---------------- K1: combined-weight precompute ----------------
// M[e] = W0[e] @ W1[e]  (bf16), c[e] = W0[e] @ b1[e] + b0[e]  (fp32)
__global__ __launch_bounds__(256) void k_prep(
    const float* __restrict__ W1, const float* __restrict__ b1,
    const float* __restrict__ W0, const float* __restrict__ b0,
    unsigned short* __restrict__ Mbf, float* __restrict__ cvec)
{
    __shared__ float s1[1024], s0[1024];
    int e = blockIdx.x, t = threadIdx.x;
    const float* w1 = W1 + e * 1024;
    const float* w0 = W0 + e * 1024;
    for (int i = t; i < 1024; i += 256) { s1[i] = w1[i]; s0[i] = w0[i]; }
    __syncthreads();
    for (int idx = t; idx < 1024; idx += 256) {
        int o = idx >> 5, i = idx & 31;
        float s = 0.f;
        #pragma unroll
        for (int k = 0; k < 32; k++) s += s0[o*32 + k] * s1[k*32 + i];
        Mbf[e*1024 + o*32 + i] = (unsigned short)f2bf(s);
    }
    if (t < DIM) {
        float s = b0[e*32 + t];
        #pragma unroll
        for (int k = 0; k < 32; k++) s += s0[t*32 + k] * b1[e*32 + k];
        cvec[e*32 + t] = s;
    }
}

// ---------------- K2: block-local bucket + LDS-staged x + MFMA + normalize ----------------
__global__ __launch_bounds__(MAIN_T, 4) void k_moe(
    const float* __restrict__ x, const int* __restrict__ pos,
    const unsigned short* __restrict__ Mbf, const float* __restrict__ cvec,
    float* __restrict__ out, int B)
{
    __shared__ unsigned short Ms[N_EXPERTS * 32 * MROW];   // 51200 B
    __shared__ unsigned short Xs[SPB * XROW];              // 20480 B (x rows as bf16)
    __shared__ float cs[N_EXPERTS * 32];                   // 2560 B
    __shared__ int hist[N_EXPERTS];
    __shared__ int lstart[N_EXPERTS + 1];
    __shared__ int cursor[N_EXPERTS];
    __shared__ int lidx[SPB];
    __shared__ int tileE[MAX_TILES], tileB[MAX_TILES];
    __shared__ int ntiles;
    // total ~75.9 KB -> 2 blocks/CU, 16 waves/CU

    int t = threadIdx.x;
    int base = blockIdx.x * SPB;
    int S = min(SPB, B - base);
    if (S <= 0) return;

    if (t < N_EXPERTS) hist[t] = 0;
    int my_e = -1;
    if (t < S) my_e = pos[base + t];
    __syncthreads();
    if (t < S) atomicAdd(&hist[my_e], 1);

    // stage M (20*1024 shorts = 10240 dwords) into padded LDS rows + cs  (L2-hot)
    {
        const uint32_t* msrc = (const uint32_t*)Mbf;
        uint32_t* mdst = (uint32_t*)Ms;
        for (int d = t; d < N_EXPERTS * 512; d += MAIN_T) {
            int e = d >> 9, rem = d & 511;
            int n = rem >> 4, c = rem & 15;
            mdst[e * (32 * MROW / 2) + n * (MROW / 2) + c] = msrc[d];
        }
        for (int i = t; i < N_EXPERTS * 32; i += MAIN_T) cs[i] = cvec[i];
    }
    // stage x rows as bf16: coalesced float4 stream, f2bf off the critical path.
    // thread handles one 16-col half-row: 2S = 512 == MAIN_T
    for (int d = t; d < 2 * S; d += MAIN_T) {
        int s = d >> 1, half = d & 1;
        const float* xr = x + (size_t)(base + s) * 32 + half * 16;
        float4 a = *(const float4*)(xr);
        float4 b = *(const float4*)(xr + 4);
        float4 c = *(const float4*)(xr + 8);
        float4 e4 = *(const float4*)(xr + 12);
        frag_ab v0, v1;
        v0[0] = f2bf(a.x); v0[1] = f2bf(a.y); v0[2] = f2bf(a.z); v0[3] = f2bf(a.w);
        v0[4] = f2bf(b.x); v0[5] = f2bf(b.y); v0[6] = f2bf(b.z); v0[7] = f2bf(b.w);
        v1[0] = f2bf(c.x); v1[1] = f2bf(c.y); v1[2] = f2bf(c.z); v1[3] = f2bf(c.w);
        v1[4] = f2bf(e4.x); v1[5] = f2bf(e4.y); v1[6] = f2bf(e4.z); v1[7] = f2bf(e4.w);
        unsigned short* xd = (unsigned short*)Xs + s * XROW + half * 16;
        *(frag_ab*)(xd)     = v0;   // byte off s*80 + half*32      : 16B aligned
        *(frag_ab*)(xd + 8) = v1;   // byte off s*80 + half*32 + 16 : 16B aligned
    }
    __syncthreads();

    int lane = t & 63, wave = t >> 6;

    // wave-0 shuffle scan: bucket starts + tile table
    if (wave == 0) {
        int e = lane;
        int h = (e < N_EXPERTS) ? hist[e] : 0;
        int s = h;
        #pragma unroll
        for (int d = 1; d < 32; d <<= 1) { int v = __shfl_up(s, d); if (lane >= d) s += v; }
        int pre = s - h;                       // exclusive prefix of counts
        int ntl = (h + 15) >> 4;
        int ts = ntl;
        #pragma unroll
        for (int d = 1; d < 32; d <<= 1) { int v = __shfl_up(ts, d); if (lane >= d) ts += v; }
        int tpre = ts - ntl;                   // exclusive prefix of tile counts
        if (e < N_EXPERTS) {
            lstart[e] = pre; cursor[e] = pre;
            for (int k = 0; k < ntl; k++) { tileE[tpre + k] = e; tileB[tpre + k] = pre + 16 * k; }
            if (e == N_EXPERTS - 1) { lstart[N_EXPERTS] = pre + h; ntiles = tpre + ntl; }
        }
    }
    __syncthreads();

    // scatter local indices
    if (t < S) {
        int slot = atomicAdd(&cursor[my_e], 1);
        lidx[slot] = t;
    }
    __syncthreads();

    int nt = ntiles;
    int n = lane & 15, q = lane >> 4;

    // tile loop: everything on the critical path is LDS-latency class now
    for (int ti = wave; ti < nt; ti += (MAIN_T / 64)) {
        int e = tileE[ti], tb = tileB[ti];
        int bend = lstart[e + 1];

        int slot = min(tb + n, bend - 1);
        int l = lidx[slot];

        // A-fragment straight from LDS bf16 rows: one ds_read_b128
        frag_ab af = *(const frag_ab*)((const unsigned short*)Xs + l * XROW + q * 8);

        // B-fragments from LDS: B[k=q*8+j][col] = M[col][k]
        const unsigned short* mrow = Ms + e * 32 * MROW;
        frag_ab bf0 = *(const frag_ab*)(mrow + n * MROW + q * 8);
        frag_ab bf1 = *(const frag_ab*)(mrow + (n + 16) * MROW + q * 8);
        float c0 = cs[e * 32 + n];
        float c1 = cs[e * 32 + 16 + n];

        frag_cd z = {0.f, 0.f, 0.f, 0.f};
        frag_cd d0 = __builtin_amdgcn_mfma_f32_16x16x32_bf16(af, bf0, z, 0, 0, 0);
        frag_cd d1 = __builtin_amdgcn_mfma_f32_16x16x32_bf16(af, bf1, z, 0, 0, 0);

        // C/D: col = lane&15 (=n), row-in-tile = q*4 + r
        #pragma unroll
        for (int r = 0; r < 4; r++) {
            int os = tb + q * 4 + r;
            float v0 = d0[r] + c0;
            float v1 = d1[r] + c1;
            float ss = v0 * v0 + v1 * v1;
            ss += __shfl_xor(ss, 1);
            ss += __shfl_xor(ss, 2);
            ss += __shfl_xor(ss, 4);
            ss += __shfl_xor(ss, 8);          // 32-dim sum of squares per sample
            float sc = rsqrtf(fmaxf(ss, 1e-24f));
            if (os < bend) {
                int lo = lidx[os];
                float* op = out + (size_t)(base + lo) * 32;
                op[n]      = v0 * sc;
                op[16 + n] = v1 * sc;
            }
        }
    }
}

extern "C" void kernel_launch(void* const* d_in, const int* in_sizes, int n_in,
                              void* d_out, int out_size, void* d_ws, size_t ws_size,
                              hipStream_t stream) {
    const float* x  = (const float*)d_in[0];
    const float* W1 = (const float*)d_in[1];
    const float* b1 = (const float*)d_in[2];
    const float* W0 = (const float*)d_in[3];
    const float* b0 = (const float*)d_in[4];
    const int*  pos = (const int*)d_in[5];
    float* out = (float*)d_out;
    int B = in_sizes[0] / DIM;   // 131072

    char* ws = (char*)d_ws;
    unsigned short* Mbf = (unsigned short*)ws;                       // 20*1024 shorts
    float* cvec = (float*)(ws + (size_t)N_EXPERTS * 1024 * 2);       // 20*32 floats

    k_prep<<<N_EXPERTS, 256, 0, stream>>>(W1, b1, W0, b0, Mbf, cvec);
    int nblk = (B + SPB - 1) / SPB;
    k_moe<<<nblk, MAIN_T, 0, stream>>>(x, pos, Mbf, cvec, out, B);
}

// Round 2
// 85.604 us; speedup vs baseline: 1.0469x; 1.0137x over previous
//
#include <hip/hip_runtime.h>
#include <stdint.h>

#define N_EXPERTS 20
#define DIM 32
#define SPB 128            // samples per block
#define MAIN_T 256         // 4 waves per block
#define XROW 40            // LDS x row stride in shorts (80 B: 16B-aligned rows, well-spread banks)
#define MAX_TILES 32       // worst case sum ceil(h_e/16) <= (128 + 20*15)/16 = 26

using frag_ab = __attribute__((ext_vector_type(8))) short;  // 8 bf16
using frag_cd = __attribute__((ext_vector_type(4))) float;  // 4 fp32

static __device__ __forceinline__ short f2bf(float f) {
    union { float f; uint32_t u; } v; v.f = f;
    uint32_t u = v.u;
    return (short)(uint16_t)((u + 0x7FFFu + ((u >> 16) & 1u)) >> 16);  // RNE
}

// ---------------- K1: combined-weight precompute ----------------
// M[e] = W0[e] @ W1[e]  (bf16), c[e] = W0[e] @ b1[e] + b0[e]  (fp32)
__global__ __launch_bounds__(256) void k_prep(
    const float* __restrict__ W1, const float* __restrict__ b1,
    const float* __restrict__ W0, const float* __restrict__ b0,
    unsigned short* __restrict__ Mbf, float* __restrict__ cvec)
{
    __shared__ float s1[1024], s0[1024];
    int e = blockIdx.x, t = threadIdx.x;
    // one float4 per thread covers the 4 KB matrix
    ((float4*)s1)[t] = ((const float4*)(W1 + e * 1024))[t];
    ((float4*)s0)[t] = ((const float4*)(W0 + e * 1024))[t];
    __syncthreads();
    for (int idx = t; idx < 1024; idx += 256) {
        int o = idx >> 5, i = idx & 31;
        float s = 0.f;
        #pragma unroll
        for (int k = 0; k < 32; k++) s += s0[o*32 + k] * s1[k*32 + i];
        Mbf[e*1024 + o*32 + i] = (unsigned short)f2bf(s);
    }
    if (t < DIM) {
        float s = b0[e*32 + t];
        #pragma unroll
        for (int k = 0; k < 32; k++) s += s0[t*32 + k] * b1[e*32 + k];
        cvec[e*32 + t] = s;
    }
}

// ---------------- K2: block-local bucket + LDS x + global-M MFMA + normalize ----------------
__global__ __launch_bounds__(MAIN_T, 4) void k_moe(
    const float* __restrict__ x, const int* __restrict__ pos,
    const unsigned short* __restrict__ Mbf, const float* __restrict__ cvec,
    float* __restrict__ out, int B)
{
    __shared__ unsigned short Xs[SPB * XROW];   // 10240 B (x rows as bf16)
    __shared__ int hist[N_EXPERTS];
    __shared__ int lstart[N_EXPERTS + 1];
    __shared__ int cursor[N_EXPERTS];
    __shared__ int lidx[SPB];
    __shared__ int tileE[MAX_TILES], tileB[MAX_TILES];
    __shared__ int ntiles;
    // total ~12 KB -> residency limited by waves (8 blocks/CU cap), grid gives 4/CU

    int t = threadIdx.x;
    int base = blockIdx.x * SPB;
    int S = min(SPB, B - base);
    if (S <= 0) return;

    // issue ALL long-latency loads up front, before any sync
    int my_e = (t < S) ? pos[base + t] : -1;

    int s_row = t >> 1, half = t & 1;
    bool xs_act = (t < 2 * S);
    float4 a, b, c, d;
    if (xs_act) {
        const float* xr = x + (size_t)(base + s_row) * 32 + half * 16;
        a = *(const float4*)(xr);
        b = *(const float4*)(xr + 4);
        c = *(const float4*)(xr + 8);
        d = *(const float4*)(xr + 12);
    }

    if (t < N_EXPERTS) hist[t] = 0;
    __syncthreads();
    if (t < S) atomicAdd(&hist[my_e], 1);

    // convert + store x rows as bf16 (padded rows)
    if (xs_act) {
        frag_ab v0, v1;
        v0[0] = f2bf(a.x); v0[1] = f2bf(a.y); v0[2] = f2bf(a.z); v0[3] = f2bf(a.w);
        v0[4] = f2bf(b.x); v0[5] = f2bf(b.y); v0[6] = f2bf(b.z); v0[7] = f2bf(b.w);
        v1[0] = f2bf(c.x); v1[1] = f2bf(c.y); v1[2] = f2bf(c.z); v1[3] = f2bf(c.w);
        v1[4] = f2bf(d.x); v1[5] = f2bf(d.y); v1[6] = f2bf(d.z); v1[7] = f2bf(d.w);
        unsigned short* xd = (unsigned short*)Xs + s_row * XROW + half * 16;
        *(frag_ab*)(xd)     = v0;
        *(frag_ab*)(xd + 8) = v1;
    }
    __syncthreads();

    int lane = t & 63, wave = t >> 6;

    // wave-0 shuffle scan: bucket starts + tile table
    if (wave == 0) {
        int e = lane;
        int h = (e < N_EXPERTS) ? hist[e] : 0;
        int s = h;
        #pragma unroll
        for (int dd = 1; dd < 32; dd <<= 1) { int v = __shfl_up(s, dd); if (lane >= dd) s += v; }
        int pre = s - h;                       // exclusive prefix of counts
        int ntl = (h + 15) >> 4;
        int ts = ntl;
        #pragma unroll
        for (int dd = 1; dd < 32; dd <<= 1) { int v = __shfl_up(ts, dd); if (lane >= dd) ts += v; }
        int tpre = ts - ntl;                   // exclusive prefix of tile counts
        if (e < N_EXPERTS) {
            lstart[e] = pre; cursor[e] = pre;
            for (int k = 0; k < ntl; k++) { tileE[tpre + k] = e; tileB[tpre + k] = pre + 16 * k; }
            if (e == N_EXPERTS - 1) { lstart[N_EXPERTS] = pre + h; ntiles = tpre + ntl; }
        }
    }
    __syncthreads();

    // scatter local indices
    if (t < S) {
        int slot = atomicAdd(&cursor[my_e], 1);
        lidx[slot] = t;
    }
    __syncthreads();

    int nt = ntiles;
    int n = lane & 15, q = lane >> 4;

    for (int ti = wave; ti < nt; ti += (MAIN_T / 64)) {
        int e = tileE[ti], tb = tileB[ti];
        int bend = lstart[e + 1];

        int slot = min(tb + n, bend - 1);
        int l = lidx[slot];

        // A-fragment from LDS bf16 rows: one ds_read_b128
        frag_ab af = *(const frag_ab*)((const unsigned short*)Xs + l * XROW + q * 8);

        // B-fragments straight from global (40 KB table, L1/L2-hot, 1 KB coalesced per wave)
        const unsigned short* me = Mbf + e * 1024;
        frag_ab bf0 = *(const frag_ab*)(me + n * 32 + q * 8);
        frag_ab bf1 = *(const frag_ab*)(me + (n + 16) * 32 + q * 8);
        float c0 = cvec[e * 32 + n];
        float c1 = cvec[e * 32 + 16 + n];

        frag_cd z = {0.f, 0.f, 0.f, 0.f};
        frag_cd d0 = __builtin_amdgcn_mfma_f32_16x16x32_bf16(af, bf0, z, 0, 0, 0);
        frag_cd d1 = __builtin_amdgcn_mfma_f32_16x16x32_bf16(af, bf1, z, 0, 0, 0);

        // C/D: col = lane&15 (=n), row-in-tile = q*4 + r
        #pragma unroll
        for (int r = 0; r < 4; r++) {
            int os = tb + q * 4 + r;
            float v0 = d0[r] + c0;
            float v1 = d1[r] + c1;
            float ss = v0 * v0 + v1 * v1;
            ss += __shfl_xor(ss, 1);
            ss += __shfl_xor(ss, 2);
            ss += __shfl_xor(ss, 4);
            ss += __shfl_xor(ss, 8);          // 32-dim sum of squares per sample
            float sc = rsqrtf(fmaxf(ss, 1e-24f));
            if (os < bend) {
                int lo = lidx[os];
                float* op = out + (size_t)(base + lo) * 32;
                __builtin_nontemporal_store(v0 * sc, op + n);
                __builtin_nontemporal_store(v1 * sc, op + 16 + n);
            }
        }
    }
}

extern "C" void kernel_launch(void* const* d_in, const int* in_sizes, int n_in,
                              void* d_out, int out_size, void* d_ws, size_t ws_size,
                              hipStream_t stream) {
    const float* x  = (const float*)d_in[0];
    const float* W1 = (const float*)d_in[1];
    const float* b1 = (const float*)d_in[2];
    const float* W0 = (const float*)d_in[3];
    const float* b0 = (const float*)d_in[4];
    const int*  pos = (const int*)d_in[5];
    float* out = (float*)d_out;
    int B = in_sizes[0] / DIM;   // 131072

    char* ws = (char*)d_ws;
    unsigned short* Mbf = (unsigned short*)ws;                       // 20*1024 shorts
    float* cvec = (float*)(ws + (size_t)N_EXPERTS * 1024 * 2);       // 20*32 floats

    k_prep<<<N_EXPERTS, 256, 0, stream>>>(W1, b1, W0, b0, Mbf, cvec);
    int nblk = (B + SPB - 1) / SPB;
    k_moe<<<nblk, MAIN_T, 0, stream>>>(x, pos, Mbf, cvec, out, B);
}